// Round 6
// baseline (136.092 us; speedup 1.0000x reference)
//
#include <hip/hip_runtime.h>

// Bilateral filter, fixed shape: x[16,3,512,512] fp32, K=5, pad=2 reflect.
// sigma_color = sigma_space = 1.1; both normalizations cancel in the ratio.
// Weight folded to one exp2: w = exp2(coef2*d^2 + coef2*sij),
// coef2 = -log2(e)/2.42; coef2*sij is a compile-time constant per tap.
// Center tap needs no special case: v_exp_f32(0) = 1.0 exactly.
//
// R3-R5 lesson: the register allocator always collapses a global-loaded
// window into a rolling load->use chain (VGPR 36/44/52), exposing L2/L3
// latency; every pipe sat >60% idle. So: stage the block halo tile in LDS
// (one coalesced pass + barrier), making all window reads ~120-cyc ds_reads
// that 4 resident blocks/CU can hide.
//
// Block = 16x16 threads, 4x4 px each -> 64x64-px tile.
// LDS tile: rows h0-2..h0+65 (68), cols w0-4..w0+67 (72 stored, stride 74).
//   stride 74: 4*74 % 32 = 8 -> the 4 ty-groups of a wave hit distinct bank
//   sets (stride 72 would alias all 4 -> 8-way conflicts); b64 reads only
//   (8B alignment holds on every row; 16B would not on odd rows).
// Reflect (pad<=H-1): idx = min(abs(i), 2*(H-1)-i), applied per element in
// the staging pass -- no special-casing anywhere else.

constexpr int H_ = 512;
constexpr int W_ = 512;
constexpr int TSTRIDE = 74;          // LDS row stride (floats)
constexpr int TROWS = 68;
constexpr int TCOLS = 72;

typedef float v2f __attribute__((ext_vector_type(2)));

__global__ __launch_bounds__(256, 4) void bilateral_kernel(
    const float* __restrict__ x,
    float* __restrict__ out)
{
    __shared__ float lds[TROWS * TSTRIDE];   // 68*74*4 = 20128 B

    int tid = threadIdx.x;
    int blk = blockIdx.x;
    int pl  = blk >> 6;              // plane (b*C+c), 48 planes
    int bi  = blk & 63;              // 8x8 blocks per plane
    int w0b = (bi & 7) << 6;         // block col origin
    int h0b = (bi >> 3) << 6;        // block row origin

    const float* plane = x + ((long)pl << 18);
    float* oplane = out + ((long)pl << 18);

    // ---- stage 68x72 halo tile into LDS (coalesced, reflect per element) ----
#pragma unroll
    for (int k = 0; k < 20; ++k) {
        int f = k * 256 + tid;
        if (f < TROWS * TCOLS) {                 // 4896
            int row = (unsigned)f / TCOLS;       // magic-mul div
            int col = f - row * TCOLS;
            int gr = h0b + row - 2;
            gr = min(abs(gr), 2 * (H_ - 1) - gr);
            int gc = w0b + col - 4;
            gc = min(abs(gc), 2 * (W_ - 1) - gc);
            lds[row * TSTRIDE + col] = plane[gr * W_ + gc];
        }
    }
    __syncthreads();

    // ---- per-thread 8x8 window from LDS ----
    int tx = tid & 15, ty = tid >> 4;
    // window row k = LDS row 4*ty + k ; window col j = LDS col 4*tx + 2 + j
    const float* wbase = lds + (ty * 4) * TSTRIDE + tx * 4 + 2;

    float Wn[8][8];
#pragma unroll
    for (int k = 0; k < 8; ++k) {
        const float* rp = wbase + k * TSTRIDE;   // 8B-aligned
#pragma unroll
        for (int j = 0; j < 8; j += 2) {
            float2 v = *(const float2*)(rp + j); // ds_read_b64
            Wn[k][j] = v.x;
            Wn[k][j + 1] = v.y;
        }
    }

    const float coef2 = -0.59615498f;            // -log2(e)/(2*1.21)
    const v2f k2 = {coef2, coef2};

#pragma unroll
    for (int oi = 0; oi < 4; ++oi) {
        v2f numA = {0.f, 0.f}, denA = {0.f, 0.f};
        v2f numB = {0.f, 0.f}, denB = {0.f, 0.f};
        v2f cA = {Wn[oi + 2][2], Wn[oi + 2][3]};
        v2f cB = {Wn[oi + 2][4], Wn[oi + 2][5]};
#pragma unroll
        for (int di = 0; di < 5; ++di) {
#pragma unroll
            for (int dj = 0; dj < 5; ++dj) {
                float csf = coef2 * (float)((di - 2) * (di - 2) +
                                            (dj - 2) * (dj - 2));
                v2f cs = {csf, csf};
                v2f pA = {Wn[oi + di][dj],     Wn[oi + di][dj + 1]};
                v2f pB = {Wn[oi + di][dj + 2], Wn[oi + di][dj + 3]};
                v2f dA = pA - cA;
                v2f dB = pB - cB;
                v2f argA = (dA * k2) * dA + cs;  // pk_mul + pk_fma
                v2f argB = (dB * k2) * dB + cs;
                v2f wA, wB;
                wA.x = __builtin_amdgcn_exp2f(argA.x);
                wA.y = __builtin_amdgcn_exp2f(argA.y);
                wB.x = __builtin_amdgcn_exp2f(argB.x);
                wB.y = __builtin_amdgcn_exp2f(argB.y);
                numA += wA * pA;
                denA += wA;
                numB += wB * pB;
                denB += wB;
            }
        }
        float4 o;
        o.x = numA.x * __builtin_amdgcn_rcpf(denA.x);
        o.y = numA.y * __builtin_amdgcn_rcpf(denA.y);
        o.z = numB.x * __builtin_amdgcn_rcpf(denB.x);
        o.w = numB.y * __builtin_amdgcn_rcpf(denB.y);
        *(float4*)(oplane + (h0b + ty * 4 + oi) * W_ + w0b + tx * 4) = o;
    }
}

extern "C" void kernel_launch(void* const* d_in, const int* in_sizes, int n_in,
                              void* d_out, int out_size, void* d_ws, size_t ws_size,
                              hipStream_t stream)
{
    const float* x = (const float*)d_in[0];
    float* out = (float*)d_out;
    int nblocks = (in_sizes[0] >> 18) * 64;   // 48 planes * 64 blocks = 3072
    bilateral_kernel<<<nblocks, 256, 0, stream>>>(x, out);
}

// Round 7
// 125.372 us; speedup vs baseline: 1.0855x; 1.0855x over previous
//
#include <hip/hip_runtime.h>

// Bilateral filter, fixed shape: x[16,3,512,512] fp32, K=5, pad=2 reflect.
// sigma_color = sigma_space = 1.1; both normalizations cancel in the ratio.
// Weight folded to one exp2: w = exp2(coef2*d^2 + coef2*sij),
// coef2 = -log2(e)/2.42; coef2*sij is a compile-time constant per tap.
// Center tap needs no special case: v_exp_f32(0) = 1.0 exactly.
//
// Structure = R5 (best, 54us): one thread = 4x4 px tile, 8x8 global-loaded
// register window, packed-fp32 tap math. R6's LDS detour regressed (67us,
// VGPR=40: compiler collapsed the window into rolling ds_read->use chains).
//
// R7 fix: __builtin_amdgcn_sched_barrier(0) between the load/pin block and
// compute. R3-R6 all show the scheduler interleaving window loads with
// compute at minimal liveness (VGPR 36/44/52/40), exposing ~24 L1/L2-latency
// stalls per tile; the mask-0 barrier forbids any instruction from crossing,
// forcing all 24 loads in flight + the 64-float window live across it ->
// one batched vmcnt drain per tile, hidden by 4-5 resident waves/SIMD.
//
// Column reflect via 2 cndmask fixups per row (verified R2-R5):
//   w0==0  : col -2 -> x[2]  = c4.z ;  w0==508: col 513 -> x[509] = c4.y
// Row reflect: r = min(abs(r), 2*(H-1)-r).

typedef float v2f __attribute__((ext_vector_type(2)));

constexpr int H_ = 512;
constexpr int W_ = 512;

__global__ __launch_bounds__(256, 4) void bilateral_kernel(
    const float* __restrict__ x,
    float* __restrict__ out,
    int nthreads)
{
    int t = blockIdx.x * 256 + threadIdx.x;
    if (t >= nthreads) return;

    int qx = t & 127;          // tile col index (4-wide tiles)
    int rg = (t >> 7) & 127;   // tile row index (4-tall tiles)
    int pl = t >> 14;          // plane (b*C + c)
    int w0 = qx << 2;
    int h0 = rg << 2;
    const float* plane = x + ((long)pl << 18);   // 512*512
    float* oplane = out + ((long)pl << 18);

    int aL = max(w0 - 2, 0);
    int aR = min(w0 + 4, W_ - 2);
    bool bL = (w0 == 0);
    bool bR = (w0 == W_ - 4);

    // Load full 8x8 window (rows h0-2..h0+5, cols w0-2..w0+5).
    float Wn[8][8];
#pragma unroll
    for (int k = 0; k < 8; ++k) {
        int r = h0 + k - 2;
        r = min(abs(r), 2 * (H_ - 1) - r);
        const float* rp = plane + r * W_;
        float2 l2 = *(const float2*)(rp + aL);
        float4 c4 = *(const float4*)(rp + w0);
        float2 r2 = *(const float2*)(rp + aR);
        Wn[k][2] = c4.x; Wn[k][3] = c4.y; Wn[k][4] = c4.z; Wn[k][5] = c4.w;
        Wn[k][0] = bL ? c4.z : l2.x;   // reflect col -2 -> +2
        Wn[k][1] = l2.y;
        Wn[k][6] = r2.x;
        Wn[k][7] = bR ? c4.y : r2.y;   // reflect col 513 -> 509
    }

    // Pin every window element into a VGPR...
#pragma unroll
    for (int k = 0; k < 8; ++k)
#pragma unroll
        for (int j = 0; j < 8; ++j)
            asm volatile("" : "+v"(Wn[k][j]));
    // ...and forbid ANY instruction from crossing this point: loads stay
    // clustered above, compute stays below, window stays live in VGPRs.
    __builtin_amdgcn_sched_barrier(0);

    const float coef2 = -0.59615498f;  // -log2(e)/(2*1.21)
    const v2f k2 = {coef2, coef2};

#pragma unroll
    for (int oi = 0; oi < 4; ++oi) {
        v2f numA = {0.f, 0.f}, denA = {0.f, 0.f};
        v2f numB = {0.f, 0.f}, denB = {0.f, 0.f};
        v2f cA = {Wn[oi + 2][2], Wn[oi + 2][3]};
        v2f cB = {Wn[oi + 2][4], Wn[oi + 2][5]};
#pragma unroll
        for (int di = 0; di < 5; ++di) {
#pragma unroll
            for (int dj = 0; dj < 5; ++dj) {
                float csf = coef2 * (float)((di - 2) * (di - 2) +
                                            (dj - 2) * (dj - 2));
                v2f cs = {csf, csf};
                v2f pA = {Wn[oi + di][dj],     Wn[oi + di][dj + 1]};
                v2f pB = {Wn[oi + di][dj + 2], Wn[oi + di][dj + 3]};
                v2f dA = pA - cA;
                v2f dB = pB - cB;
                v2f argA = (dA * k2) * dA + cs;  // pk_mul + pk_fma
                v2f argB = (dB * k2) * dB + cs;
                v2f wA, wB;
                wA.x = __builtin_amdgcn_exp2f(argA.x);
                wA.y = __builtin_amdgcn_exp2f(argA.y);
                wB.x = __builtin_amdgcn_exp2f(argB.x);
                wB.y = __builtin_amdgcn_exp2f(argB.y);
                numA += wA * pA;
                denA += wA;
                numB += wB * pB;
                denB += wB;
            }
        }
        float4 o;
        o.x = numA.x * __builtin_amdgcn_rcpf(denA.x);
        o.y = numA.y * __builtin_amdgcn_rcpf(denA.y);
        o.z = numB.x * __builtin_amdgcn_rcpf(denB.x);
        o.w = numB.y * __builtin_amdgcn_rcpf(denB.y);
        *(float4*)(oplane + (h0 + oi) * W_ + w0) = o;
    }
}

extern "C" void kernel_launch(void* const* d_in, const int* in_sizes, int n_in,
                              void* d_out, int out_size, void* d_ws, size_t ws_size,
                              hipStream_t stream)
{
    const float* x = (const float*)d_in[0];
    float* out = (float*)d_out;
    int nthreads = in_sizes[0] >> 4;         // 16 px per thread
    int blocks = (nthreads + 255) / 256;
    bilateral_kernel<<<blocks, 256, 0, stream>>>(x, out, nthreads);
}